// Round 16
// baseline (346.694 us; speedup 1.0000x reference)
//
#include <hip/hip_runtime.h>
#include <math.h>

#define H 4096
#define W 4096
#define NC 512            // cells per dim (H/8)
#define NB 510            // blocks per dim (NC - 3 + 1)
#define ORI 9
#define NCELLS (NC * NC)  // 262144
#define NOUT (NB * NB * 81)  // 21068100

// ---- glibc flt-32 atanf/atan2f replication (fdlibm; pre-2.40 glibc) ----
__device__ __forceinline__ float fdlibm_atanf(float x) {
#pragma clang fp contract(off)
    const float one = 1.0f;
    const float aT0  = (float) 3.33333333333329318027e-01;
    const float aT1  = (float)-1.99999999998764832476e-01;
    const float aT2  = (float) 1.42857142725034663711e-01;
    const float aT3  = (float)-1.11111104054623557880e-01;
    const float aT4  = (float) 9.09088713343650656196e-02;
    const float aT5  = (float)-7.69187620504482999495e-02;
    const float aT6  = (float) 6.66107313738753120669e-02;
    const float aT7  = (float)-5.83357013379057348645e-02;
    const float aT8  = (float) 4.97687799461593236017e-02;
    const float aT9  = (float)-3.65315727442169155270e-02;
    const float aT10 = (float) 1.62858201153657823623e-02;
    const float athi[4] = {4.6364760399e-01f, 7.8539812565e-01f,
                           9.8279368877e-01f, 1.5707962513e+00f};
    const float atlo[4] = {5.0121582440e-09f, 3.7748947079e-08f,
                           3.4473217170e-08f, 7.5497894159e-08f};
    int hx = __float_as_int(x);
    int ix = hx & 0x7fffffff;
    int id;
    if (ix >= 0x4c800000) {
        if (ix > 0x7f800000) return x + x;
        float r = athi[3] + atlo[3];
        return (hx > 0) ? r : -r;
    }
    if (ix < 0x3ee00000) {
        if (ix < 0x31000000) return x;
        id = -1;
    } else {
        x = fabsf(x);
        if (ix < 0x3f980000) {
            if (ix < 0x3f300000) { id = 0; x = (2.0f * x - one) / (2.0f + x); }
            else                 { id = 1; x = (x - one) / (x + one); }
        } else {
            if (ix < 0x401c0000) { id = 2; x = (x - 1.5f) / (one + 1.5f * x); }
            else                 { id = 3; x = -1.0f / x; }
        }
    }
    float z = x * x;
    float w = z * z;
    float s1 = z * (aT0 + w * (aT2 + w * (aT4 + w * (aT6 + w * (aT8 + w * aT10)))));
    float s2 = w * (aT1 + w * (aT3 + w * (aT5 + w * (aT7 + w * aT9))));
    if (id < 0) return x - x * (s1 + s2);
    z = athi[id] - ((x * (s1 + s2) - atlo[id]) - x);
    return (hx < 0) ? -z : z;
}

__device__ __forceinline__ float fdlibm_atan2f(float y, float x) {
#pragma clang fp contract(off)
    const float tiny   = 1.0e-30f;
    const float pi     = 3.1415927410e+00f;
    const float pi_lo  = -8.7422776573e-08f;
    const float pi_o_2 = 1.5707963705e+00f;
    int hx = __float_as_int(x), ix = hx & 0x7fffffff;
    int hy = __float_as_int(y), iy = hy & 0x7fffffff;
    if (hx == 0x3f800000) return fdlibm_atanf(y);
    int m = ((hy >> 31) & 1) | ((hx >> 30) & 2);
    if (iy == 0) {
        switch (m) {
            case 0: case 1: return y;
            case 2: return pi + tiny;
            default: return -pi - tiny;
        }
    }
    if (ix == 0) return (hy < 0) ? -pi_o_2 - tiny : pi_o_2 + tiny;
    int k = (iy - ix) >> 23;
    float z;
    if (k > 26) { z = pi_o_2 + 0.5f * pi_lo; m &= 1; }
    else if (k < -26 && hx < 0) z = 0.0f;
    else z = fdlibm_atanf(fabsf(y / x));
    switch (m) {
        case 0: return z;
        case 1: return -z;
        case 2: return pi - (z - pi_lo);
        default: return (z - pi_lo) - pi;
    }
}

// EXACT bin for pixel (reload + IEEE pipeline). 0..8 or 9 (excluded).
__device__ __forceinline__ int slow_bin_px(const float* __restrict__ x,
                                           int grow, int gc,
                                           bool row_ok, bool col_ok) {
#pragma clang fp contract(off)
    float gy = 0.0f, gx = 0.0f;
    if (row_ok)
        gy = sqrtf(x[(grow + 1) * W + gc]) - sqrtf(x[(grow - 1) * W + gc]);
    if (col_ok)
        gx = sqrtf(x[grow * W + gc + 1]) - sqrtf(x[grow * W + gc - 1]);
    float ang = fdlibm_atan2f(gy, gx);
    const float RAD2DEG = (float)(180.0 / 3.14159265358979323846264338328);
    float deg = ang * RAD2DEG;
    float m = fmodf(deg, 180.0f);
    if (m < 0.0f) m += 180.0f;
    int bin = (int)(m / 20.0f);
    if (bin < 9 && m >= (float)((bin + 1) * 20)) bin++;
    else if (bin > 0 && m < (float)(bin * 20)) bin--;
    return bin;
}

#define T20 ((float) 0.36397023426620236135)
#define T40 ((float) 0.83909963117728001176)
#define T60 ((float) 1.73205080756887729353)
#define T80 ((float) 5.67128181961771110517)

// fast tangent bin; returns bin and cm (boundary distance) via ref
__device__ __forceinline__ int fast_bin(float gy, float gx, float& cm, float& ab) {
    float a = fabsf(gy), b = fabsf(gx);
    float d1 = fmaf(b, -T20, a);
    float d2 = fmaf(b, -T40, a);
    float d3 = fmaf(b, -T60, a);
    float d4 = fmaf(b, -T80, a);
    int cnt = (d1 > 0.0f) + (d2 > 0.0f) + (d3 > 0.0f) + (d4 > 0.0f);
    bool opp = ((__float_as_int(gy) ^ __float_as_int(gx)) < 0);
    cm = fminf(fminf(fabsf(d1), fabsf(d2)),
               fminf(fminf(fabsf(d3), fabsf(d4)), a));
    ab = a + b;
    return opp ? 8 - cnt : cnt;
}

// ================= V4: real kernel (r15 verbatim) =================
__global__ __launch_bounds__(256) void hog_hist(const float* __restrict__ x,
                                                float* __restrict__ hist,
                                                float* __restrict__ q) {
    __shared__ float lh[4 * 72];
    int t = threadIdx.x;
    int w = t >> 6, lane = t & 63;
    int wid = blockIdx.x * 4 + w;
    int crow = wid >> 6;
    int strip = wid & 63;
    int col0 = strip << 6;
    int gc = col0 + lane;

    lh[w * 72 + lane] = 0.0f;
    if (lane < 8) lh[w * 72 + 64 + lane] = 0.0f;

    int r0 = (crow << 3) - 1;
    bool ok0 = (crow > 0), ok9 = (crow < NC - 1);
    float s[10];
    s[0] = __builtin_amdgcn_sqrtf(ok0 ? x[(r0 + 0) * W + gc] : 0.0f);
#pragma unroll
    for (int k = 1; k < 9; ++k) s[k] = __builtin_amdgcn_sqrtf(x[(r0 + k) * W + gc]);
    s[9] = __builtin_amdgcn_sqrtf(ok9 ? x[(r0 + 9) * W + gc] : 0.0f);

    bool col_ok = (gc >= 1) && (gc <= W - 2);
    float* lw = &lh[w * 72 + (lane >> 3) * 9];

#pragma unroll
    for (int j = 0; j < 8; ++j) {
        int grow = (crow << 3) + j;
        bool row_ok = (grow >= 1) && (grow <= H - 2);
        float gy = row_ok ? (s[j + 2] - s[j]) : 0.0f;
        float sl = 0.0f, sr = 0.0f;
        if (col_ok) {
            sl = __builtin_amdgcn_sqrtf(x[grow * W + gc - 1]);
            sr = __builtin_amdgcn_sqrtf(x[grow * W + gc + 1]);
        }
        float gx = sr - sl;
        float cm, ab;
        int bin = fast_bin(gy, gx, cm, ab);
        if (cm < fmaf(1e-5f, ab, 4e-6f))
            bin = slow_bin_px(x, grow, gc, row_ok, col_ok);
        float mag = __builtin_amdgcn_sqrtf(fmaf(gy, gy, gx * gx));
        if (bin < ORI) atomicAdd(&lw[bin], mag);
    }

    int cbase = crow * (NC * ORI) + strip * 72;
    hist[cbase + lane] = lh[w * 72 + lane] * (1.0f / 64.0f);
    if (lane < 8) {
        hist[cbase + 64 + lane] = lh[w * 72 + 64 + lane] * (1.0f / 64.0f);
        float qq = 0.0f;
#pragma unroll
        for (int o = 0; o < 9; ++o) {
            float h = lh[w * 72 + lane * 9 + o] * (1.0f / 64.0f);
            qq = fmaf(h, h, qq);
        }
        q[crow * NC + strip * 8 + lane] = qq;
    }
}

// ================= V1: compute ON, memory OFF (synth data) =================
__device__ __forceinline__ float synthv(int r, int c) {
    unsigned u = (unsigned)(r * W + c) * 2654435761u;
    return __int_as_float(0x3F000000 | (u >> 9));   // [0.5, 1)
}
__global__ __launch_bounds__(256) void hv1_noload(float* __restrict__ scratch) {
    __shared__ float lh[4 * 72];
    int t = threadIdx.x;
    int w = t >> 6, lane = t & 63;
    int wid = blockIdx.x * 4 + w;
    int crow = wid >> 6;
    int strip = wid & 63;
    int gc = (strip << 6) + lane;
    lh[w * 72 + lane] = 0.0f;
    if (lane < 8) lh[w * 72 + 64 + lane] = 0.0f;
    int r0 = (crow << 3) - 1;
    bool ok0 = (crow > 0), ok9 = (crow < NC - 1);
    float s[10];
    s[0] = __builtin_amdgcn_sqrtf(ok0 ? synthv(r0, gc) : 0.0f);
#pragma unroll
    for (int k = 1; k < 9; ++k) s[k] = __builtin_amdgcn_sqrtf(synthv(r0 + k, gc));
    s[9] = __builtin_amdgcn_sqrtf(ok9 ? synthv(r0 + 9, gc) : 0.0f);
    bool col_ok = (gc >= 1) && (gc <= W - 2);
    float* lw = &lh[w * 72 + (lane >> 3) * 9];
#pragma unroll
    for (int j = 0; j < 8; ++j) {
        int grow = (crow << 3) + j;
        bool row_ok = (grow >= 1) && (grow <= H - 2);
        float gy = row_ok ? (s[j + 2] - s[j]) : 0.0f;
        float sl = 0.0f, sr = 0.0f;
        if (col_ok) {
            sl = __builtin_amdgcn_sqrtf(synthv(grow, gc - 1));
            sr = __builtin_amdgcn_sqrtf(synthv(grow, gc + 1));
        }
        float gx = sr - sl;
        float cm, ab;
        int bin = fast_bin(gy, gx, cm, ab);
        if (cm < fmaf(1e-5f, ab, 4e-6f)) {   // synth slow path (no loads)
            float gye = row_ok ? (sqrtf(synthv(grow + 1, gc)) - sqrtf(synthv(grow - 1, gc))) : 0.0f;
            float gxe = col_ok ? (sqrtf(synthv(grow, gc + 1)) - sqrtf(synthv(grow, gc - 1))) : 0.0f;
            float ang = fdlibm_atan2f(gye, gxe);
            float deg = ang * (float)(180.0 / 3.14159265358979323846264338328);
            float m = fmodf(deg, 180.0f);
            if (m < 0.0f) m += 180.0f;
            bin = (int)(m / 20.0f);
        }
        float mag = __builtin_amdgcn_sqrtf(fmaf(gy, gy, gx * gx));
        if (bin < ORI) atomicAdd(&lw[bin], mag);
    }
    scratch[wid * 64 + lane] = lh[w * 72 + lane];
}

// ================= V2: memory ON, compute OFF (load pattern only) =========
__global__ __launch_bounds__(256) void hv2_loadonly(const float* __restrict__ x,
                                                    float* __restrict__ scratch) {
    int t = threadIdx.x;
    int w = t >> 6, lane = t & 63;
    int wid = blockIdx.x * 4 + w;
    int crow = wid >> 6;
    int strip = wid & 63;
    int gc = (strip << 6) + lane;
    int r0 = (crow << 3) - 1;
    bool ok0 = (crow > 0), ok9 = (crow < NC - 1);
    float acc = 0.0f;
    acc += ok0 ? x[(r0 + 0) * W + gc] : 0.0f;
#pragma unroll
    for (int k = 1; k < 9; ++k) acc += x[(r0 + k) * W + gc];
    acc += ok9 ? x[(r0 + 9) * W + gc] : 0.0f;
    bool col_ok = (gc >= 1) && (gc <= W - 2);
#pragma unroll
    for (int j = 0; j < 8; ++j) {
        int grow = (crow << 3) + j;
        if (col_ok) {
            acc += x[grow * W + gc - 1];
            acc += x[grow * W + gc + 1];
        }
    }
    scratch[wid * 64 + lane] = acc;
}

// ================= V5: candidate fix — all loads hoisted, branchless ======
__global__ __launch_bounds__(256, 4) void hv5_hoist(const float* __restrict__ x,
                                                    float* __restrict__ scratch) {
    __shared__ float lh[4 * 80];   // 8 cells x 10 bins (slot 9 = dummy)
    int t = threadIdx.x;
    int w = t >> 6, lane = t & 63;
    int wid = blockIdx.x * 4 + w;
    int crow = wid >> 6;
    int strip = wid & 63;
    int gc = (strip << 6) + lane;
    lh[w * 80 + lane] = 0.0f;
    if (lane < 16) lh[w * 80 + 64 + lane] = 0.0f;

    int r0 = (crow << 3) - 1;
    int rtop = (r0 < 0) ? 0 : r0;
    int rbot = (r0 + 9 > H - 1) ? (H - 1) : (r0 + 9);
    int gcl = (gc == 0) ? 0 : gc - 1;
    int gcr = (gc == W - 1) ? (W - 1) : gc + 1;

    // ---- ALL 26 loads issued with no intervening control flow ----
    float s[10], slv[8], srv[8];
    s[0] = x[rtop * W + gc];
#pragma unroll
    for (int k = 1; k < 9; ++k) s[k] = x[(r0 + k) * W + gc];
    s[9] = x[rbot * W + gc];
#pragma unroll
    for (int j = 0; j < 8; ++j) {
        int grow = (crow << 3) + j;
        slv[j] = x[grow * W + gcl];
        srv[j] = x[grow * W + gcr];
    }
#pragma unroll
    for (int k = 0; k < 10; ++k) s[k] = __builtin_amdgcn_sqrtf(s[k]);
#pragma unroll
    for (int j = 0; j < 8; ++j) {
        slv[j] = __builtin_amdgcn_sqrtf(slv[j]);
        srv[j] = __builtin_amdgcn_sqrtf(srv[j]);
    }
    bool col_ok = (gc >= 1) && (gc <= W - 2);
    float* lw = &lh[w * 80 + (lane >> 3) * 10];
#pragma unroll
    for (int j = 0; j < 8; ++j) {
        int grow = (crow << 3) + j;
        bool row_ok = (grow >= 1) && (grow <= H - 2);
        float gy = row_ok ? (s[j + 2] - s[j]) : 0.0f;
        float gx = col_ok ? (srv[j] - slv[j]) : 0.0f;
        float cm, ab;
        int bin = fast_bin(gy, gx, cm, ab);
        if (cm < fmaf(1e-5f, ab, 4e-6f))
            bin = slow_bin_px(x, grow, gc, row_ok, col_ok);
        float mag = __builtin_amdgcn_sqrtf(fmaf(gy, gy, gx * gx));
        atomicAdd(&lw[bin], mag);    // bin 9 -> dummy slot, no branch
    }
    // digest (scratch only)
    scratch[wid * 64 + lane] = lh[w * 80 + lane];
    if (lane < 16) scratch[wid * 64 + (lane & 7)] += lh[w * 80 + 64 + lane];
}

// ================= B and C (real) =================
__global__ __launch_bounds__(256) void hog_inv(const float* __restrict__ q,
                                               float* __restrict__ inv) {
    int t = blockIdx.x * 256 + threadIdx.x;
    if (t >= NB * NB) return;
    int i = t / NB;
    int j = t - i * NB;
    float ssq = 0.0f;
#pragma unroll
    for (int bi = 0; bi < 3; ++bi)
#pragma unroll
        for (int bj = 0; bj < 3; ++bj)
            ssq += q[(i + bi) * NC + (j + bj)];
    inv[t] = 1.0f / sqrtf(ssq + 1e-10f);
}

__global__ __launch_bounds__(256) void hog_norm(const float* __restrict__ hist,
                                                const float* __restrict__ inv,
                                                float* __restrict__ out, int n) {
    int k = blockIdx.x * 256 + threadIdx.x;
    if (k >= n) return;
    int pidx = k / 81;
    int e = k - pidx * 81;
    int i = pidx / NB;
    int j = pidx - i * NB;
    int bi = e / 27;
    int r = e - bi * 27;
    int bj = r / 9;
    int o = r - bj * 9;
    out[k] = hist[((i + bi) * NC + (j + bj)) * ORI + o] * inv[pidx];
}

extern "C" void kernel_launch(void* const* d_in, const int* in_sizes, int n_in,
                              void* d_out, int out_size, void* d_ws, size_t ws_size,
                              hipStream_t stream) {
    const float* x = (const float*)d_in[0];
    float* out = (float*)d_out;
    float* hist = (float*)d_ws;                     // 9.44 MB
    float* inv  = hist + NCELLS * ORI;              // 1.04 MB
    float* q = out + (NOUT - NCELLS);               // d_out tail (overwritten by C)

    // diagnostic variants (scratch in d_out regions later overwritten by C)
    hv1_noload<<<(NC * 64) / 4, 256, 0, stream>>>(out);
    hv2_loadonly<<<(NC * 64) / 4, 256, 0, stream>>>(x, out + 4 * 1024 * 1024);
    hv5_hoist<<<(NC * 64) / 4, 256, 0, stream>>>(x, out + 8 * 1024 * 1024);

    // real pipeline
    hog_hist<<<(NC * 64) / 4, 256, 0, stream>>>(x, hist, q);
    hog_inv<<<(NB * NB + 255) / 256, 256, 0, stream>>>(q, inv);
    hog_norm<<<(out_size + 255) / 256, 256, 0, stream>>>(hist, inv, out, out_size);
}

// Round 17
// 76.019 us; speedup vs baseline: 4.5606x; 4.5606x over previous
//
#include <hip/hip_runtime.h>
#include <math.h>

#define H 4096
#define W 4096
#define NC 512            // cells per dim (H/8)
#define NB 510            // blocks per dim (NC - 3 + 1)
#define ORI 9
#define NCELLS (NC * NC)  // 262144
#define NOUT (NB * NB * 81)  // 21068100

// ---- glibc flt-32 atanf/atan2f replication (fdlibm; pre-2.40 glibc) ----
__device__ __forceinline__ float fdlibm_atanf(float x) {
#pragma clang fp contract(off)
    const float one = 1.0f;
    const float aT0  = (float) 3.33333333333329318027e-01;
    const float aT1  = (float)-1.99999999998764832476e-01;
    const float aT2  = (float) 1.42857142725034663711e-01;
    const float aT3  = (float)-1.11111104054623557880e-01;
    const float aT4  = (float) 9.09088713343650656196e-02;
    const float aT5  = (float)-7.69187620504482999495e-02;
    const float aT6  = (float) 6.66107313738753120669e-02;
    const float aT7  = (float)-5.83357013379057348645e-02;
    const float aT8  = (float) 4.97687799461593236017e-02;
    const float aT9  = (float)-3.65315727442169155270e-02;
    const float aT10 = (float) 1.62858201153657823623e-02;
    const float athi[4] = {4.6364760399e-01f, 7.8539812565e-01f,
                           9.8279368877e-01f, 1.5707962513e+00f};
    const float atlo[4] = {5.0121582440e-09f, 3.7748947079e-08f,
                           3.4473217170e-08f, 7.5497894159e-08f};
    int hx = __float_as_int(x);
    int ix = hx & 0x7fffffff;
    int id;
    if (ix >= 0x4c800000) {
        if (ix > 0x7f800000) return x + x;
        float r = athi[3] + atlo[3];
        return (hx > 0) ? r : -r;
    }
    if (ix < 0x3ee00000) {
        if (ix < 0x31000000) return x;
        id = -1;
    } else {
        x = fabsf(x);
        if (ix < 0x3f980000) {
            if (ix < 0x3f300000) { id = 0; x = (2.0f * x - one) / (2.0f + x); }
            else                 { id = 1; x = (x - one) / (x + one); }
        } else {
            if (ix < 0x401c0000) { id = 2; x = (x - 1.5f) / (one + 1.5f * x); }
            else                 { id = 3; x = -1.0f / x; }
        }
    }
    float z = x * x;
    float w = z * z;
    float s1 = z * (aT0 + w * (aT2 + w * (aT4 + w * (aT6 + w * (aT8 + w * aT10)))));
    float s2 = w * (aT1 + w * (aT3 + w * (aT5 + w * (aT7 + w * aT9))));
    if (id < 0) return x - x * (s1 + s2);
    z = athi[id] - ((x * (s1 + s2) - atlo[id]) - x);
    return (hx < 0) ? -z : z;
}

__device__ __forceinline__ float fdlibm_atan2f(float y, float x) {
#pragma clang fp contract(off)
    const float tiny   = 1.0e-30f;
    const float pi     = 3.1415927410e+00f;
    const float pi_lo  = -8.7422776573e-08f;
    const float pi_o_2 = 1.5707963705e+00f;
    int hx = __float_as_int(x), ix = hx & 0x7fffffff;
    int hy = __float_as_int(y), iy = hy & 0x7fffffff;
    if (hx == 0x3f800000) return fdlibm_atanf(y);
    int m = ((hy >> 31) & 1) | ((hx >> 30) & 2);
    if (iy == 0) {
        switch (m) {
            case 0: case 1: return y;
            case 2: return pi + tiny;
            default: return -pi - tiny;
        }
    }
    if (ix == 0) return (hy < 0) ? -pi_o_2 - tiny : pi_o_2 + tiny;
    int k = (iy - ix) >> 23;
    float z;
    if (k > 26) { z = pi_o_2 + 0.5f * pi_lo; m &= 1; }
    else if (k < -26 && hx < 0) z = 0.0f;
    else z = fdlibm_atanf(fabsf(y / x));
    switch (m) {
        case 0: return z;
        case 1: return -z;
        case 2: return pi - (z - pi_lo);
        default: return (z - pi_lo) - pi;
    }
}

// EXACT bin for pixel (reload + IEEE pipeline). 0..8 or 9 (excluded).
__device__ __forceinline__ int slow_bin_px(const float* __restrict__ x,
                                           int grow, int gc,
                                           bool row_ok, bool col_ok) {
#pragma clang fp contract(off)
    float gy = 0.0f, gx = 0.0f;
    if (row_ok)
        gy = sqrtf(x[(grow + 1) * W + gc]) - sqrtf(x[(grow - 1) * W + gc]);
    if (col_ok)
        gx = sqrtf(x[grow * W + gc + 1]) - sqrtf(x[grow * W + gc - 1]);
    float ang = fdlibm_atan2f(gy, gx);
    const float RAD2DEG = (float)(180.0 / 3.14159265358979323846264338328);
    float deg = ang * RAD2DEG;
    float m = fmodf(deg, 180.0f);
    if (m < 0.0f) m += 180.0f;
    int bin = (int)(m / 20.0f);
    if (bin < 9 && m >= (float)((bin + 1) * 20)) bin++;
    else if (bin > 0 && m < (float)(bin * 20)) bin--;
    return bin;
}

#define T20 ((float) 0.36397023426620236135)
#define T40 ((float) 0.83909963117728001176)
#define T60 ((float) 1.73205080756887729353)
#define T80 ((float) 5.67128181961771110517)

__device__ __forceinline__ int fast_bin(float gy, float gx, float& cm, float& ab) {
    float a = fabsf(gy), b = fabsf(gx);
    float d1 = fmaf(b, -T20, a);
    float d2 = fmaf(b, -T40, a);
    float d3 = fmaf(b, -T60, a);
    float d4 = fmaf(b, -T80, a);
    int cnt = (d1 > 0.0f) + (d2 > 0.0f) + (d3 > 0.0f) + (d4 > 0.0f);
    bool opp = ((__float_as_int(gy) ^ __float_as_int(gx)) < 0);
    cm = fminf(fminf(fabsf(d1), fabsf(d2)),
               fminf(fminf(fabsf(d3), fabsf(d4)), a));
    ab = a + b;
    return opp ? 8 - cnt : cnt;
}

// Kernel A: ZERO LDS, zero atomics. Wave = 8x64 px strip; lane = one column;
// a lane's 8 pixels all belong to one cell (cell = lane>>3). Histogram kept
// in 9 per-lane registers (select-accumulate), reduced over the 8-lane cell
// group by a 3-step shfl_xor butterfly, written straight to global.
// (r16 bisection: hv1_noload == plateau -> LDS-atomic serialization was the
// floor since r5; ds_add_f32 same-address RMWs serialize in the LDS pipe.)
__global__ __launch_bounds__(256) void hog_hist(const float* __restrict__ x,
                                                float* __restrict__ hist,
                                                float* __restrict__ q) {
    int t = threadIdx.x;
    int w = t >> 6, lane = t & 63;
    int wid = blockIdx.x * 4 + w;
    int crow = wid >> 6;            // cell row 0..511
    int strip = wid & 63;           // 64-col strip
    int gc = (strip << 6) + lane;   // this lane's image column

    // 10 row loads at column gc (rows crow*8-1 .. crow*8+8), fast sqrt
    int r0 = (crow << 3) - 1;
    bool ok0 = (crow > 0), ok9 = (crow < NC - 1);
    float s[10];
    s[0] = __builtin_amdgcn_sqrtf(ok0 ? x[(r0 + 0) * W + gc] : 0.0f);
#pragma unroll
    for (int k = 1; k < 9; ++k) s[k] = __builtin_amdgcn_sqrtf(x[(r0 + k) * W + gc]);
    s[9] = __builtin_amdgcn_sqrtf(ok9 ? x[(r0 + 9) * W + gc] : 0.0f);

    bool col_ok = (gc >= 1) && (gc <= W - 2);
    float acc[9];
#pragma unroll
    for (int b = 0; b < 9; ++b) acc[b] = 0.0f;

#pragma unroll
    for (int j = 0; j < 8; ++j) {
        int grow = (crow << 3) + j;
        bool row_ok = (grow >= 1) && (grow <= H - 2);   // wave-uniform
        float gy = row_ok ? (s[j + 2] - s[j]) : 0.0f;
        float sl = 0.0f, sr = 0.0f;
        if (col_ok) {
            sl = __builtin_amdgcn_sqrtf(x[grow * W + gc - 1]);
            sr = __builtin_amdgcn_sqrtf(x[grow * W + gc + 1]);
        }
        float gx = sr - sl;

        float cm, ab;
        int bin = fast_bin(gy, gx, cm, ab);
        if (cm < fmaf(1e-5f, ab, 4e-6f))
            bin = slow_bin_px(x, grow, gc, row_ok, col_ok);

        float mag = __builtin_amdgcn_sqrtf(fmaf(gy, gy, gx * gx)); // value-level
        // select-accumulate: bin 9 (m==180 quirk) matches nothing -> excluded
#pragma unroll
        for (int b = 0; b < 9; ++b) acc[b] += (bin == b) ? mag : 0.0f;
    }

    // butterfly reduce over the 8-lane cell group (xor 1,2,4)
#pragma unroll
    for (int st = 1; st <= 4; st <<= 1) {
#pragma unroll
        for (int b = 0; b < 9; ++b) acc[b] += __shfl_xor(acc[b], st, 64);
    }

    // writes: lane k of each cell group writes bin k; k==0 also writes bin 8
    int cell = lane >> 3;
    int k = lane & 7;
    int cbase = crow * (NC * ORI) + strip * 72 + cell * 9;
    float hv = acc[0];
#pragma unroll
    for (int b = 1; b < 8; ++b) hv = (k == b) ? acc[b] : hv;   // const-idx select
    hist[cbase + k] = hv * (1.0f / 64.0f);
    if (k == 0) {
        hist[cbase + 8] = acc[8] * (1.0f / 64.0f);
        float qq = 0.0f;
#pragma unroll
        for (int b = 0; b < 9; ++b) {
            float h = acc[b] * (1.0f / 64.0f);
            qq = fmaf(h, h, qq);
        }
        q[crow * NC + strip * 8 + cell] = qq;
    }
}

// Kernel B: inv(i,j) = rsqrt(3x3 box-sum of q + EPS^2)
__global__ __launch_bounds__(256) void hog_inv(const float* __restrict__ q,
                                               float* __restrict__ inv) {
    int t = blockIdx.x * 256 + threadIdx.x;
    if (t >= NB * NB) return;
    int i = t / NB;
    int j = t - i * NB;
    float ssq = 0.0f;
#pragma unroll
    for (int bi = 0; bi < 3; ++bi)
#pragma unroll
        for (int bj = 0; bj < 3; ++bj)
            ssq += q[(i + bi) * NC + (j + bj)];
    inv[t] = 1.0f / sqrtf(ssq + 1e-10f);
}

// Kernel C: thread per output element, coalesced stores.
__global__ __launch_bounds__(256) void hog_norm(const float* __restrict__ hist,
                                                const float* __restrict__ inv,
                                                float* __restrict__ out, int n) {
    int k = blockIdx.x * 256 + threadIdx.x;
    if (k >= n) return;
    int pidx = k / 81;
    int e = k - pidx * 81;
    int i = pidx / NB;
    int j = pidx - i * NB;
    int bi = e / 27;
    int r = e - bi * 27;
    int bj = r / 9;
    int o = r - bj * 9;
    out[k] = hist[((i + bi) * NC + (j + bj)) * ORI + o] * inv[pidx];
}

extern "C" void kernel_launch(void* const* d_in, const int* in_sizes, int n_in,
                              void* d_out, int out_size, void* d_ws, size_t ws_size,
                              hipStream_t stream) {
    const float* x = (const float*)d_in[0];
    float* out = (float*)d_out;
    float* hist = (float*)d_ws;                     // 9.44 MB
    float* inv  = hist + NCELLS * ORI;              // 1.04 MB
    float* q = out + (NOUT - NCELLS);               // d_out tail (overwritten by C)

    hog_hist<<<(NC * 64) / 4, 256, 0, stream>>>(x, hist, q);   // 8192 blocks
    hog_inv<<<(NB * NB + 255) / 256, 256, 0, stream>>>(q, inv);
    hog_norm<<<(out_size + 255) / 256, 256, 0, stream>>>(hist, inv, out, out_size);
}